// Round 6
// baseline (395.342 us; speedup 1.0000x reference)
//
#include <hip/hip_runtime.h>
#include <math.h>

// Problem constants
constexpr int NB = 8, ND = 8, NP = 512 * 1024, NG = NP / 4, NK = 5;
constexpr int BPB  = 128;           // blocks per image
constexpr int NBLK = NB * BPB;      // 1024 blocks
constexpr int GPB  = NG / BPB;      // 1024 float4-groups per block
constexpr int ITER = GPB / 256;     // 4 iterations per thread
constexpr int PSTR = 48;            // 40 sums + 5 cnts + pad

constexpr float DELTA_V = 0.5f, TWO_DELTA_D = 6.0f, GAMMA = 0.001f;
#define SCOPE __HIP_MEMORY_SCOPE_AGENT

// ws float layout:
//   int[0]            global done counter (K2)
//   int[8..15]        per-image done counters (K1 tail)
//   [64   .. 64+8*64)   centers [8 images][6 rows][8] (row 0 = zeros)  plain
//   [1024 .. 1024+8*48) totals  [8][48]                               plain
//   [2048 .. 2048+NBLK*8) per-block vsum partials (release/atomic)
//   [16384.. 16384+45*NBLK) K1 partials TRANSPOSED [45][NBLK] (release/atomic)
constexpr int OFF_CEN = 64, OFF_TOT = 1024, OFF_VP = 2048, OFF_P1 = 16384;

__device__ __forceinline__ float wave_sum(float v) {
#pragma unroll
    for (int off = 32; off > 0; off >>= 1) v += __shfl_down(v, off, 64);
    return v;
}

// ---------------- K0: zero the done counters ----------------
__global__ void k0_init(int* wsi) {
    if (threadIdx.x < 64) wsi[threadIdx.x] = 0;
}

// ---------------- K1: per-block sums/counts; last block per image reduces ----
__global__ __launch_bounds__(256) void k1_partials(
    const float* __restrict__ emb, const int* __restrict__ mask,
    float* __restrict__ ws)
{
    int* const wsi = (int*)ws;
    const int b   = blockIdx.x / BPB;
    const int blk = blockIdx.x % BPB;
    const float4* emb4 = (const float4*)emb + (size_t)b * ND * NG;
    const int4*   m4   = (const int4*)mask + (size_t)b * NG;

    float acc[NK][ND], cnt[NK];
#pragma unroll
    for (int k = 0; k < NK; ++k) {
        cnt[k] = 0.f;
#pragma unroll
        for (int d = 0; d < ND; ++d) acc[k][d] = 0.f;
    }

    // 2-deep software pipeline: iteration i+1's 9 loads live across i's compute.
    int g = blk * GPB + threadIdx.x;
    int4 mc = m4[g];
    float4 ec[ND];
#pragma unroll
    for (int d = 0; d < ND; ++d) ec[d] = emb4[(size_t)d * NG + g];

#pragma unroll
    for (int i = 0; i < ITER; ++i) {
        int4 mn;
        float4 en[ND];
        if (i + 1 < ITER) {
            const int gn = g + 256;
            mn = m4[gn];
#pragma unroll
            for (int d = 0; d < ND; ++d) en[d] = emb4[(size_t)d * NG + gn];
        }
        const int labs[4] = {mc.x, mc.y, mc.z, mc.w};
#pragma unroll
        for (int j = 0; j < 4; ++j) {
            const int lab = labs[j];
#pragma unroll
            for (int k = 0; k < NK; ++k) {
                const bool sel = (lab == k + 1);
                cnt[k] += sel ? 1.f : 0.f;
#pragma unroll
                for (int d = 0; d < ND; ++d)
                    acc[k][d] += sel ? ((const float*)&ec[d])[j] : 0.f;
            }
        }
        if (i + 1 < ITER) {
            mc = mn;
#pragma unroll
            for (int d = 0; d < ND; ++d) ec[d] = en[d];
            g += 256;
        }
    }

    __shared__ float part[4][PSTR];
    const int lane = threadIdx.x & 63, wave = threadIdx.x >> 6;
#pragma unroll
    for (int k = 0; k < NK; ++k) {
#pragma unroll
        for (int d = 0; d < ND; ++d) {
            const float r = wave_sum(acc[k][d]);
            if (lane == 0) part[wave][k * ND + d] = r;
        }
        const float rc = wave_sum(cnt[k]);
        if (lane == 0) part[wave][NK * ND + k] = rc;
    }
    __syncthreads();
    if (threadIdx.x < 45) {
        const float s = part[0][threadIdx.x] + part[1][threadIdx.x] +
                        part[2][threadIdx.x] + part[3][threadIdx.x];
        // agent-scope release store: consumed within this kernel by the tail block
        __hip_atomic_store(&ws[OFF_P1 + (size_t)threadIdx.x * NBLK + blockIdx.x],
                           s, __ATOMIC_RELEASE, SCOPE);
    }
    __syncthreads();

    // per-image done counter; last block reduces this image's 128 partials
    __shared__ bool amlast;
    if (threadIdx.x == 0) {
        const int old = __hip_atomic_fetch_add(&wsi[8 + b], 1, __ATOMIC_ACQ_REL, SCOPE);
        amlast = (old == BPB - 1);
    }
    __syncthreads();
    if (!amlast) return;

    __shared__ float red1[45][4];
    __shared__ float csh[PSTR];
    if (threadIdx.x < 180) {
        const int v = threadIdx.x >> 2, q = threadIdx.x & 3;
        const float* p = ws + OFF_P1 + (size_t)v * NBLK + b * BPB + q * 32;
        float s = 0.f;
#pragma unroll
        for (int i = 0; i < 32; ++i)
            s += __hip_atomic_load(&p[i], __ATOMIC_RELAXED, SCOPE);
        red1[v][q] = s;
    }
    __syncthreads();
    if (threadIdx.x < 45) {
        const float s = red1[threadIdx.x][0] + red1[threadIdx.x][1] +
                        red1[threadIdx.x][2] + red1[threadIdx.x][3];
        csh[threadIdx.x] = s;
        ws[OFF_TOT + b * PSTR + threadIdx.x] = s;   // plain: K2 reads after boundary
    }
    __syncthreads();
    if (threadIdx.x < 48) {   // centers [6][8], row 0 = zeros (background)
        const int row = threadIdx.x >> 3, d = threadIdx.x & 7;
        float v = 0.f;
        if (row > 0)
            v = csh[(row - 1) * ND + d] / fmaxf(csh[NK * ND + (row - 1)], 1.f);
        ws[OFF_CEN + b * 64 + threadIdx.x] = v;     // plain: boundary syncs
    }
}

// ---------------- K2: hinge pass + last-block epilogue ----------------
__global__ __launch_bounds__(256) void k2_hinge(
    const float* __restrict__ emb, const int* __restrict__ mask,
    float* __restrict__ ws, float* __restrict__ out)
{
    int* const wsi = (int*)ws;
    const int b   = blockIdx.x / BPB;
    const int blk = blockIdx.x % BPB;

    __shared__ float cLDS[6][ND];
    __shared__ float part[4][8];
    __shared__ bool  amlast;

    if (threadIdx.x < 48)   // centers written by K1 tail; kernel boundary syncs
        cLDS[threadIdx.x >> 3][threadIdx.x & 7] = ws[OFF_CEN + b * 64 + threadIdx.x];
    __syncthreads();

    const float4* emb4 = (const float4*)emb + (size_t)b * ND * NG;
    const int4*   m4   = (const int4*)mask + (size_t)b * NG;

    float vacc[NK] = {0.f, 0.f, 0.f, 0.f, 0.f};

    int g = blk * GPB + threadIdx.x;
    int4 mc = m4[g];
    float4 ec[ND];
#pragma unroll
    for (int d = 0; d < ND; ++d) ec[d] = emb4[(size_t)d * NG + g];

#pragma unroll
    for (int i = 0; i < ITER; ++i) {
        int4 mn;
        float4 en[ND];
        if (i + 1 < ITER) {
            const int gn = g + 256;
            mn = m4[gn];
#pragma unroll
            for (int d = 0; d < ND; ++d) en[d] = emb4[(size_t)d * NG + gn];
        }
        const int labs[4] = {mc.x, mc.y, mc.z, mc.w};
#pragma unroll
        for (int j = 0; j < 4; ++j) {
            const int lab = labs[j];
            const float4* crow = (const float4*)&cLDS[lab][0];
            const float4 c0 = crow[0], c1 = crow[1];
            const float cd[8] = {c0.x, c0.y, c0.z, c0.w, c1.x, c1.y, c1.z, c1.w};
            float dsq = 0.f;
#pragma unroll
            for (int d = 0; d < ND; ++d) {
                const float diff = ((const float*)&ec[d])[j] - cd[d];
                dsq = fmaf(diff, diff, dsq);
            }
            const float hv = fmaxf(sqrtf(dsq) - DELTA_V, 0.f);
            const float val = hv * hv;
#pragma unroll
            for (int k = 0; k < NK; ++k)
                vacc[k] += (lab == k + 1) ? val : 0.f;
        }
        if (i + 1 < ITER) {
            mc = mn;
#pragma unroll
            for (int d = 0; d < ND; ++d) ec[d] = en[d];
            g += 256;
        }
    }

    const int lane = threadIdx.x & 63, wave = threadIdx.x >> 6;
#pragma unroll
    for (int k = 0; k < NK; ++k) {
        const float r = wave_sum(vacc[k]);
        if (lane == 0) part[wave][k] = r;
    }
    __syncthreads();
    if (threadIdx.x < NK) {
        const float s = part[0][threadIdx.x] + part[1][threadIdx.x] +
                        part[2][threadIdx.x] + part[3][threadIdx.x];
        __hip_atomic_store(&ws[OFF_VP + (size_t)blockIdx.x * 8 + threadIdx.x], s,
                           __ATOMIC_RELEASE, SCOPE);
    }
    __syncthreads();
    if (threadIdx.x == 0) {
        const int old = __hip_atomic_fetch_add(&wsi[0], 1, __ATOMIC_ACQ_REL, SCOPE);
        amlast = (old == NBLK - 1);
    }
    __syncthreads();
    if (!amlast) return;

    // ---- last block: gather per-image vsums + totals, compute the loss ----
    __shared__ float vred[NB][NK][4];
    __shared__ float tsh[NB][PSTR];
    if (threadIdx.x < 160) {
        const int bb = threadIdx.x / 20, r = threadIdx.x % 20;
        const int k = r >> 2, q = r & 3;
        float s = 0.f;
#pragma unroll
        for (int i = 0; i < 32; ++i)
            s += __hip_atomic_load(&ws[OFF_VP + (size_t)(bb * BPB + q * 32 + i) * 8 + k],
                                   __ATOMIC_RELAXED, SCOPE);
        vred[bb][k][q] = s;
    }
    for (int t = threadIdx.x; t < NB * PSTR; t += 256) {
        const int bb = t / PSTR, j = t % PSTR;
        tsh[bb][j] = ws[OFF_TOT + bb * PSTR + j];   // written by K1; boundary syncs
    }
    __syncthreads();
    if (threadIdx.x == 0) {
        float tv = 0.f, td = 0.f, tr = 0.f, hs = 0.f;
        for (int bb = 0; bb < NB; ++bb) {
            float cc[NK], CC[NK][ND];
            bool pres[NK];
            float N = 0.f;
            for (int k = 0; k < NK; ++k) {
                cc[k] = tsh[bb][NK * ND + k];
                pres[k] = cc[k] > 0.f;
                if (pres[k]) N += 1.f;
                const float inv = 1.f / fmaxf(cc[k], 1.f);
                for (int d = 0; d < ND; ++d)
                    CC[k][d] = tsh[bb][k * ND + d] * inv;
            }
            float lv = 0.f;
            for (int k = 0; k < NK; ++k)
                if (pres[k]) {
                    const float vs = vred[bb][k][0] + vred[bb][k][1] +
                                     vred[bb][k][2] + vred[bb][k][3];
                    lv += vs / fmaxf(cc[k], 1.f);
                }
            lv /= fmaxf(N, 1.f);

            float ld = 0.f;
            for (int i2 = 0; i2 < NK; ++i2)
                for (int j2 = i2 + 1; j2 < NK; ++j2)
                    if (pres[i2] && pres[j2]) {
                        float dsq = 0.f;
                        for (int d = 0; d < ND; ++d) {
                            const float df = CC[i2][d] - CC[j2][d];
                            dsq = fmaf(df, df, dsq);
                        }
                        const float t = fmaxf(TWO_DELTA_D - sqrtf(dsq), 0.f);
                        ld += t * t;
                    }
            const float npairs = N * (N - 1.f) * 0.5f;
            ld /= (N > 1.f) ? npairs : 1.f;

            float lr = 0.f;
            for (int k = 0; k < NK; ++k)
                if (pres[k]) {
                    float sq = 0.f;
                    for (int d = 0; d < ND; ++d) sq = fmaf(CC[k][d], CC[k][d], sq);
                    lr += sqrtf(sq);
                }
            lr /= fmaxf(N, 1.f);

            if (N > 0.f) { tv += lv; td += ld; tr += lr; hs += 1.f; }
        }
        const float den = fmaxf(hs, 1.f);
        tv /= den; td /= den; tr /= den;
        out[0] = tv + td + GAMMA * tr;
        out[1] = tv;
        out[2] = td;
        out[3] = tr;
    }
}

extern "C" void kernel_launch(void* const* d_in, const int* in_sizes, int n_in,
                              void* d_out, int out_size, void* d_ws, size_t ws_size,
                              hipStream_t stream) {
    const float* emb  = (const float*)d_in[0];
    const int*   mask = (const int*)d_in[1];
    float* ws = (float*)d_ws;
    k0_init<<<dim3(1), dim3(64), 0, stream>>>((int*)ws);
    k1_partials<<<dim3(NBLK), dim3(256), 0, stream>>>(emb, mask, ws);
    k2_hinge<<<dim3(NBLK), dim3(256), 0, stream>>>(emb, mask, ws, (float*)d_out);
}